// Round 21
// baseline (271.292 us; speedup 1.0000x reference)
//
#include <hip/hip_runtime.h>
#include <hip/hip_fp16.h>

// B=8192, T=512, IN=1, H=20, OUT=1
#define B_TOTAL 8192
#define TILE    8                   // batches per block (8 -> 1024 blocks = 4/CU)
#define T_LEN   512
#define H       20
#define KSTEP   4
#define NSUPER  (T_LEN / KSTEP)     // 128
#define CHUNK   128                 // x timesteps staged at once (32 super-ticks)
#define XSTRC   132                 // chunk row stride: 132%32=4 -> <=2-way (free)

typedef _Float16 f16x4 __attribute__((ext_vector_type(4)));
typedef float    f32x4 __attribute__((ext_vector_type(4)));
typedef unsigned int u32;

// 16x16x16 f16 MFMA (R18-validated): D lane(b,g) rows j=4g+r ; B lane(b,g)
// k=4g+i -> tanh(D)+pack IS next step's B-fragment, zero cross-lane ops.
#if defined(__HIP_DEVICE_COMPILE__)
  #if __has_builtin(__builtin_amdgcn_mfma_f32_16x16x16_f16)
    #define MFMA16(a, b, c) __builtin_amdgcn_mfma_f32_16x16x16_f16((a), (b), (c), 0, 0, 0)
  #elif __has_builtin(__builtin_amdgcn_mfma_f32_16x16x16f16)
    #define MFMA16(a, b, c) __builtin_amdgcn_mfma_f32_16x16x16f16((a), (b), (c), 0, 0, 0)
  #else
    #error "no 16x16x16 f16 MFMA builtin on device"
  #endif
#else
  #define MFMA16(a, b, c) (c)   // host parse stub
#endif

__device__ __forceinline__ float fast_tanh(float x) {
    float e = __builtin_amdgcn_exp2f(x * 2.885390081777927f);
    return fmaf(-2.0f, __builtin_amdgcn_rcpf(e + 1.0f), 1.0f);
}
__device__ __forceinline__ u32 pk2(float a, float b) {
    return __builtin_bit_cast(u32, __builtin_amdgcn_cvt_pkrtz(a, b));
}
__device__ __forceinline__ f16x4 u2f(uint2 v) { return __builtin_bit_cast(f16x4, v); }

// ---- prologue: pack 5 HxH matrices into 16x16x16 A-fragments (R18 verbatim) ----
__global__ void prep_w(const float* __restrict__ w_hh0, const float* __restrict__ w_ih1,
                       const float* __restrict__ w_hh1, const float* __restrict__ w_ih2,
                       const float* __restrict__ w_hh2, u32* __restrict__ ws)
{
    for (int e = threadIdx.x; e < 5 * 4 * 64; e += 256) {
        int l = e & 63, f = (e >> 6) & 3, m = e >> 8;
        const float* src = (m == 0) ? w_hh0 : (m == 1) ? w_ih1 :
                           (m == 2) ? w_hh1 : (m == 3) ? w_ih2 : w_hh2;
        int p = l & 15, g = l >> 4;
        int row = (f & 2) ? 16 + p : p;
        int kb  = ((f & 1) ? 16 : 0) + 4 * g;
        u32 d0 = 0, d1 = 0;
        if (row < H) {
            unsigned short h[4];
            #pragma unroll
            for (int i = 0; i < 4; ++i) {
                int k = kb + i;
                _Float16 v = (k < H) ? (_Float16)src[row * H + k] : (_Float16)0.f;
                h[i] = __builtin_bit_cast(unsigned short, v);
            }
            d0 = (u32)h[0] | ((u32)h[1] << 16);
            d1 = (u32)h[2] | ((u32)h[3] << 16);
        }
        ws[e * 2 + 0] = d0;
        ws[e * 2 + 1] = d1;
    }
}

// tanh(D1,D2) -> packed f16 state + uint4 for LDS handoff
#define TANHPK4(lo, hi, pkd, D1, D2) { \
    u32 a0 = pk2(fast_tanh((D1)[0]), fast_tanh((D1)[1])); \
    u32 a1 = pk2(fast_tanh((D1)[2]), fast_tanh((D1)[3])); \
    u32 a2 = pk2(fast_tanh((D2)[0]), fast_tanh((D2)[1])); \
    u32 a3 = pk2(fast_tanh((D2)[2]), fast_tanh((D2)[3])); \
    lo = u2f(make_uint2(a0, a1)); \
    hi = u2f(make_uint2(a2, a3)); \
    pkd = make_uint4(a0, a1, a2, a3); \
}

// 3 waves/block (one layer each), 8 batches/block (MFMA cols 8-15 = benign
// garbage: zero weights / never stored). 1024 blocks -> 4 blocks/CU, 12
// waves/CU: barrier-phase-shifted blocks fill each other's latency gaps.
__global__ __launch_bounds__(192, 3) void rnn_mfma(
    const float* __restrict__ x,
    const float* __restrict__ w_ih0,
    const float* __restrict__ b_ih0, const float* __restrict__ b_hh0,
    const float* __restrict__ b_ih1, const float* __restrict__ b_hh1,
    const float* __restrict__ b_ih2, const float* __restrict__ b_hh2,
    const float* __restrict__ fc_w,  const float* __restrict__ fc_b,
    const u32* __restrict__ wpk,
    float* __restrict__ out)
{
    __shared__ __align__(16) float xs[16][XSTRC];        // rows 8-15 stay zero
    __shared__ __align__(16) uint4 h0b[2][KSTEP][64];    // wv0 -> wv1, slot = lane
    __shared__ __align__(16) uint4 h1b[2][KSTEP][64];    // wv1 -> wv2, slot = lane

    const int tid = threadIdx.x;
    const int wv  = tid >> 6;
    const int l   = tid & 63;
    const int b   = l & 15;
    const int g   = l >> 4;
    const int gb0 = blockIdx.x * TILE;

    // ---- zero dummy xs rows once; stage x chunk 0 (rows 0-7) ----
    for (int i = tid; i < 8 * XSTRC; i += 192) xs[8 + i / XSTRC][i % XSTRC] = 0.f;
    for (int i = tid; i < TILE * (CHUNK / 4); i += 192) {
        int row = i >> 5, col4 = i & 31;
        *(float4*)&xs[row][col4 * 4] =
            *(const float4*)(x + (size_t)(gb0 + row) * T_LEN + col4 * 4);
    }

    // ---- per-wave weight A-fragments ----
    const int mA = (wv == 1) ? 1 : 3;
    const int mB = (wv == 0) ? 0 : (wv == 1) ? 2 : 4;
    f16x4 IAlo1 = {}, IAhi1 = {}, IAlo2 = {}, IAhi2 = {};
    if (wv != 0) {
        IAlo1 = u2f(*(const uint2*)(wpk + ((mA * 4 + 0) * 64 + l) * 2));
        IAhi1 = u2f(*(const uint2*)(wpk + ((mA * 4 + 1) * 64 + l) * 2));
        IAlo2 = u2f(*(const uint2*)(wpk + ((mA * 4 + 2) * 64 + l) * 2));
        IAhi2 = u2f(*(const uint2*)(wpk + ((mA * 4 + 3) * 64 + l) * 2));
    }
    const f16x4 RAlo1 = u2f(*(const uint2*)(wpk + ((mB * 4 + 0) * 64 + l) * 2));
    const f16x4 RAhi1 = u2f(*(const uint2*)(wpk + ((mB * 4 + 1) * 64 + l) * 2));
    const f16x4 RAlo2 = u2f(*(const uint2*)(wpk + ((mB * 4 + 2) * 64 + l) * 2));
    const f16x4 RAhi2 = u2f(*(const uint2*)(wpk + ((mB * 4 + 3) * 64 + l) * 2));

    // ---- biases in D layout (tile1: j=4g+r; tile2: j=16+r on g==0) ----
    const float* bi = (wv == 0) ? b_ih0 : (wv == 1) ? b_ih1 : b_ih2;
    const float* bh = (wv == 0) ? b_hh0 : (wv == 1) ? b_hh1 : b_hh2;
    f32x4 bd1, bd2, w0lo, w0hi;
    #pragma unroll
    for (int r = 0; r < 4; ++r) {
        int j = 4 * g + r;
        bd1[r]  = bi[j] + bh[j];
        bd2[r]  = (g == 0) ? bi[16 + r] + bh[16 + r] : 0.f;
        w0lo[r] = w_ih0[j];
        w0hi[r] = (g == 0) ? w_ih0[16 + r] : 0.f;
    }

    // ---- recurrent state (own layer), in registers ----
    f16x4 Hlo = {}, Hhi = {};

    for (int m = 0; m < NSUPER + 2; ++m) {
        __syncthreads();
        if (wv == 0) {
            if (m < NSUPER) {
                // restage next x chunk when crossing a 128-step boundary
                if (m > 0 && (m & 31) == 0) {
                    const int tc = (m >> 5) * CHUNK;
                    for (int i = l; i < TILE * (CHUNK / 4); i += 64) {
                        int row = i >> 5, col4 = i & 31;
                        *(float4*)&xs[row][col4 * 4] =
                            *(const float4*)(x + (size_t)(gb0 + row) * T_LEN + tc + col4 * 4);
                    }
                }
                f32x4 P1[KSTEP], P2[KSTEP];
                #pragma unroll
                for (int s = 0; s < KSTEP; ++s) {
                    int tl = (KSTEP * m + s) & (CHUNK - 1);
                    float xv = xs[b][tl];
                    #pragma unroll
                    for (int r = 0; r < 4; ++r) {
                        P1[s][r] = fmaf(xv, w0lo[r], bd1[r]);
                        P2[s][r] = fmaf(xv, w0hi[r], bd2[r]);
                    }
                }
                #pragma unroll
                for (int s = 0; s < KSTEP; ++s) {
                    f32x4 D1 = MFMA16(RAlo1, Hlo, P1[s]); D1 = MFMA16(RAhi1, Hhi, D1);
                    f32x4 D2 = MFMA16(RAlo2, Hlo, P2[s]); D2 = MFMA16(RAhi2, Hhi, D2);
                    uint4 pk;
                    TANHPK4(Hlo, Hhi, pk, D1, D2)
                    h0b[m & 1][s][l] = pk;
                }
            }
        } else if (wv == 1) {
            if (m >= 1 && m <= NSUPER) {
                f32x4 P1[KSTEP], P2[KSTEP];
                #pragma unroll
                for (int s = 0; s < KSTEP; ++s) {
                    uint4 v = h0b[(m - 1) & 1][s][l];
                    f16x4 Blo = u2f(make_uint2(v.x, v.y));
                    f16x4 Bhi = u2f(make_uint2(v.z, v.w));
                    P1[s] = MFMA16(IAlo1, Blo, bd1); P1[s] = MFMA16(IAhi1, Bhi, P1[s]);
                    P2[s] = MFMA16(IAlo2, Blo, bd2); P2[s] = MFMA16(IAhi2, Bhi, P2[s]);
                }
                #pragma unroll
                for (int s = 0; s < KSTEP; ++s) {
                    f32x4 D1 = MFMA16(RAlo1, Hlo, P1[s]); D1 = MFMA16(RAhi1, Hhi, D1);
                    f32x4 D2 = MFMA16(RAlo2, Hlo, P2[s]); D2 = MFMA16(RAhi2, Hhi, D2);
                    uint4 pk;
                    TANHPK4(Hlo, Hhi, pk, D1, D2)
                    h1b[(m - 1) & 1][s][l] = pk;
                }
            }
        } else {
            if (m >= 2) {
                f32x4 P1[KSTEP], P2[KSTEP];
                #pragma unroll
                for (int s = 0; s < KSTEP; ++s) {
                    uint4 v = h1b[m & 1][s][l];          // (m-2)&1 == m&1
                    f16x4 Blo = u2f(make_uint2(v.x, v.y));
                    f16x4 Bhi = u2f(make_uint2(v.z, v.w));
                    P1[s] = MFMA16(IAlo1, Blo, bd1); P1[s] = MFMA16(IAhi1, Bhi, P1[s]);
                    P2[s] = MFMA16(IAlo2, Blo, bd2); P2[s] = MFMA16(IAhi2, Bhi, P2[s]);
                }
                #pragma unroll
                for (int s = 0; s < KSTEP; ++s) {
                    f32x4 D1 = MFMA16(RAlo1, Hlo, P1[s]); D1 = MFMA16(RAhi1, Hhi, D1);
                    f32x4 D2 = MFMA16(RAlo2, Hlo, P2[s]); D2 = MFMA16(RAhi2, Hhi, D2);
                    uint4 pk;
                    TANHPK4(Hlo, Hhi, pk, D1, D2)
                }
            }
        }
    }

    // ---- FC epilogue: wave2 holds h2(511); only batches 0-7 are real ----
    if (wv == 2) {
        float acc = 0.f;
        #pragma unroll
        for (int i = 0; i < 4; ++i)
            acc = fmaf((float)Hlo[i], fc_w[4 * g + i], acc);
        if (g == 0) {
            #pragma unroll
            for (int i = 0; i < 4; ++i)
                acc = fmaf((float)Hhi[i], fc_w[16 + i], acc);
        }
        acc += __shfl_xor(acc, 16);
        acc += __shfl_xor(acc, 32);
        if (l < TILE) out[gb0 + l] = acc + fc_b[0];
    }
}

extern "C" void kernel_launch(void* const* d_in, const int* in_sizes, int n_in,
                              void* d_out, int out_size, void* d_ws, size_t ws_size,
                              hipStream_t stream) {
    const float* x     = (const float*)d_in[0];
    const float* w_ih0 = (const float*)d_in[1];
    const float* w_hh0 = (const float*)d_in[2];
    const float* b_ih0 = (const float*)d_in[3];
    const float* b_hh0 = (const float*)d_in[4];
    const float* w_ih1 = (const float*)d_in[5];
    const float* w_hh1 = (const float*)d_in[6];
    const float* b_ih1 = (const float*)d_in[7];
    const float* b_hh1 = (const float*)d_in[8];
    const float* w_ih2 = (const float*)d_in[9];
    const float* w_hh2 = (const float*)d_in[10];
    const float* b_ih2 = (const float*)d_in[11];
    const float* b_hh2 = (const float*)d_in[12];
    const float* fc_w  = (const float*)d_in[13];
    const float* fc_b  = (const float*)d_in[14];
    float* out = (float*)d_out;
    u32* wpk = (u32*)d_ws;   // 5 * 4 * 64 * 2 * 4 = 10240 B

    prep_w<<<1, 256, 0, stream>>>(w_hh0, w_ih1, w_hh1, w_ih2, w_hh2, wpk);

    rnn_mfma<<<B_TOTAL / TILE, 192, 0, stream>>>(
        x, w_ih0, b_ih0, b_hh0, b_ih1, b_hh1, b_ih2, b_hh2,
        fc_w, fc_b, wpk, out);
}

// Round 22
// 166.862 us; speedup vs baseline: 1.6258x; 1.6258x over previous
//
#include <hip/hip_runtime.h>
#include <hip/hip_fp16.h>

// B=8192, T=512, IN=1, H=20, OUT=1
#define B_TOTAL 8192
#define T_LEN   512
#define H       20
#define XSTR    516            // xs row stride (floats): 516%32=4 -> <=2-way (free)
#define KSTEP   8              // timesteps per barrier
#define NSUPER  (T_LEN / KSTEP)   // 64

typedef _Float16 f16x4 __attribute__((ext_vector_type(4)));
typedef float    f32x4 __attribute__((ext_vector_type(4)));
typedef unsigned int u32;

// 16x16x16 f16 MFMA (R18-validated): D lane(b,g) rows j=4g+r ; B lane(b,g)
// k=4g+i -> tanh(D)+pack IS next step's B-fragment, zero cross-lane ops.
#if defined(__HIP_DEVICE_COMPILE__)
  #if __has_builtin(__builtin_amdgcn_mfma_f32_16x16x16_f16)
    #define MFMA16(a, b, c) __builtin_amdgcn_mfma_f32_16x16x16_f16((a), (b), (c), 0, 0, 0)
  #elif __has_builtin(__builtin_amdgcn_mfma_f32_16x16x16f16)
    #define MFMA16(a, b, c) __builtin_amdgcn_mfma_f32_16x16x16f16((a), (b), (c), 0, 0, 0)
  #else
    #error "no 16x16x16 f16 MFMA builtin on device"
  #endif
#else
  #define MFMA16(a, b, c) (c)   // host parse stub
#endif

__device__ __forceinline__ float fast_tanh(float x) {
    float e = __builtin_amdgcn_exp2f(x * 2.885390081777927f);
    return fmaf(-2.0f, __builtin_amdgcn_rcpf(e + 1.0f), 1.0f);
}
__device__ __forceinline__ u32 pk2(float a, float b) {
    return __builtin_bit_cast(u32, __builtin_amdgcn_cvt_pkrtz(a, b));
}
__device__ __forceinline__ f16x4 u2f(uint2 v) { return __builtin_bit_cast(f16x4, v); }

// ---- prologue: pack 5 HxH matrices into 16x16x16 A-fragments (R18 verbatim) ----
__global__ void prep_w(const float* __restrict__ w_hh0, const float* __restrict__ w_ih1,
                       const float* __restrict__ w_hh1, const float* __restrict__ w_ih2,
                       const float* __restrict__ w_hh2, u32* __restrict__ ws)
{
    for (int e = threadIdx.x; e < 5 * 4 * 64; e += 256) {
        int l = e & 63, f = (e >> 6) & 3, m = e >> 8;
        const float* src = (m == 0) ? w_hh0 : (m == 1) ? w_ih1 :
                           (m == 2) ? w_hh1 : (m == 3) ? w_ih2 : w_hh2;
        int p = l & 15, g = l >> 4;
        int row = (f & 2) ? 16 + p : p;
        int kb  = ((f & 1) ? 16 : 0) + 4 * g;
        u32 d0 = 0, d1 = 0;
        if (row < H) {
            unsigned short h[4];
            #pragma unroll
            for (int i = 0; i < 4; ++i) {
                int k = kb + i;
                _Float16 v = (k < H) ? (_Float16)src[row * H + k] : (_Float16)0.f;
                h[i] = __builtin_bit_cast(unsigned short, v);
            }
            d0 = (u32)h[0] | ((u32)h[1] << 16);
            d1 = (u32)h[2] | ((u32)h[3] << 16);
        }
        ws[e * 2 + 0] = d0;
        ws[e * 2 + 1] = d1;
    }
}

// tanh(D1,D2) -> packed f16 state + uint4 for LDS handoff
#define TANHPK4(lo, hi, pkd, D1, D2) { \
    u32 a0 = pk2(fast_tanh((D1)[0]), fast_tanh((D1)[1])); \
    u32 a1 = pk2(fast_tanh((D1)[2]), fast_tanh((D1)[3])); \
    u32 a2 = pk2(fast_tanh((D2)[0]), fast_tanh((D2)[1])); \
    u32 a3 = pk2(fast_tanh((D2)[2]), fast_tanh((D2)[3])); \
    lo = u2f(make_uint2(a0, a1)); \
    hi = u2f(make_uint2(a2, a3)); \
    pkd = make_uint4(a0, a1, a2, a3); \
}

// wave-role superticks (KSTEP steps each). Numerics identical to R18.
#define W0SUP(m) { \
    f32x4 P1[KSTEP], P2[KSTEP]; \
    _Pragma("unroll") \
    for (int s = 0; s < KSTEP; ++s) { \
        float xv = xs[b][KSTEP * (m) + s]; \
        _Pragma("unroll") \
        for (int r = 0; r < 4; ++r) { \
            P1[s][r] = fmaf(xv, w0lo[r], bd1[r]); \
            P2[s][r] = fmaf(xv, w0hi[r], bd2[r]); \
        } \
    } \
    _Pragma("unroll") \
    for (int s = 0; s < KSTEP; ++s) { \
        f32x4 D1 = MFMA16(RAlo1, Hlo, P1[s]); D1 = MFMA16(RAhi1, Hhi, D1); \
        f32x4 D2 = MFMA16(RAlo2, Hlo, P2[s]); D2 = MFMA16(RAhi2, Hhi, D2); \
        uint4 pk; \
        TANHPK4(Hlo, Hhi, pk, D1, D2) \
        h0b[(m) & 1][s][l] = pk; \
    } \
}

#define W1SUP(m) { \
    f32x4 P1[KSTEP], P2[KSTEP]; \
    _Pragma("unroll") \
    for (int s = 0; s < KSTEP; ++s) { \
        uint4 v = h0b[((m) - 1) & 1][s][l]; \
        f16x4 Blo = u2f(make_uint2(v.x, v.y)); \
        f16x4 Bhi = u2f(make_uint2(v.z, v.w)); \
        P1[s] = MFMA16(IAlo1, Blo, bd1); P1[s] = MFMA16(IAhi1, Bhi, P1[s]); \
        P2[s] = MFMA16(IAlo2, Blo, bd2); P2[s] = MFMA16(IAhi2, Bhi, P2[s]); \
    } \
    _Pragma("unroll") \
    for (int s = 0; s < KSTEP; ++s) { \
        f32x4 D1 = MFMA16(RAlo1, Hlo, P1[s]); D1 = MFMA16(RAhi1, Hhi, D1); \
        f32x4 D2 = MFMA16(RAlo2, Hlo, P2[s]); D2 = MFMA16(RAhi2, Hhi, D2); \
        uint4 pk; \
        TANHPK4(Hlo, Hhi, pk, D1, D2) \
        h1b[((m) - 1) & 1][s][l] = pk; \
    } \
}

#define W2SUP(m) { \
    f32x4 P1[KSTEP], P2[KSTEP]; \
    _Pragma("unroll") \
    for (int s = 0; s < KSTEP; ++s) { \
        uint4 v = h1b[(m) & 1][s][l]; \
        f16x4 Blo = u2f(make_uint2(v.x, v.y)); \
        f16x4 Bhi = u2f(make_uint2(v.z, v.w)); \
        P1[s] = MFMA16(IAlo1, Blo, bd1); P1[s] = MFMA16(IAhi1, Bhi, P1[s]); \
        P2[s] = MFMA16(IAlo2, Blo, bd2); P2[s] = MFMA16(IAhi2, Bhi, P2[s]); \
    } \
    _Pragma("unroll") \
    for (int s = 0; s < KSTEP; ++s) { \
        f32x4 D1 = MFMA16(RAlo1, Hlo, P1[s]); D1 = MFMA16(RAhi1, Hhi, D1); \
        f32x4 D2 = MFMA16(RAlo2, Hlo, P2[s]); D2 = MFMA16(RAhi2, Hhi, D2); \
        uint4 pk; \
        TANHPK4(Hlo, Hhi, pk, D1, D2) \
    } \
}

// 3 waves/block (one layer each), 16 batches/block, KSTEP=8, peeled pipeline:
// steady-state loop has no range conditionals, x fully staged (no restage).
__global__ __launch_bounds__(192, 2) void rnn_mfma(
    const float* __restrict__ x,
    const float* __restrict__ w_ih0,
    const float* __restrict__ b_ih0, const float* __restrict__ b_hh0,
    const float* __restrict__ b_ih1, const float* __restrict__ b_hh1,
    const float* __restrict__ b_ih2, const float* __restrict__ b_hh2,
    const float* __restrict__ fc_w,  const float* __restrict__ fc_b,
    const u32* __restrict__ wpk,
    float* __restrict__ out)
{
    __shared__ __align__(16) float xs[16][XSTR];         // all 512 steps resident
    __shared__ __align__(16) uint4 h0b[2][KSTEP][64];    // wv0 -> wv1, slot = lane
    __shared__ __align__(16) uint4 h1b[2][KSTEP][64];    // wv1 -> wv2, slot = lane

    const int tid = threadIdx.x;
    const int wv  = tid >> 6;
    const int l   = tid & 63;
    const int b   = l & 15;
    const int g   = l >> 4;
    const int gb0 = blockIdx.x * 16;

    // ---- stage ALL x (coalesced float4), once ----
    for (int i = tid; i < 16 * 128; i += 192) {
        int row = i >> 7, col4 = i & 127;
        *(float4*)&xs[row][col4 * 4] =
            *(const float4*)(x + (size_t)(gb0 + row) * T_LEN + col4 * 4);
    }

    // ---- per-wave weight A-fragments ----
    const int mA = (wv == 1) ? 1 : 3;
    const int mB = (wv == 0) ? 0 : (wv == 1) ? 2 : 4;
    f16x4 IAlo1 = {}, IAhi1 = {}, IAlo2 = {}, IAhi2 = {};
    if (wv != 0) {
        IAlo1 = u2f(*(const uint2*)(wpk + ((mA * 4 + 0) * 64 + l) * 2));
        IAhi1 = u2f(*(const uint2*)(wpk + ((mA * 4 + 1) * 64 + l) * 2));
        IAlo2 = u2f(*(const uint2*)(wpk + ((mA * 4 + 2) * 64 + l) * 2));
        IAhi2 = u2f(*(const uint2*)(wpk + ((mA * 4 + 3) * 64 + l) * 2));
    }
    const f16x4 RAlo1 = u2f(*(const uint2*)(wpk + ((mB * 4 + 0) * 64 + l) * 2));
    const f16x4 RAhi1 = u2f(*(const uint2*)(wpk + ((mB * 4 + 1) * 64 + l) * 2));
    const f16x4 RAlo2 = u2f(*(const uint2*)(wpk + ((mB * 4 + 2) * 64 + l) * 2));
    const f16x4 RAhi2 = u2f(*(const uint2*)(wpk + ((mB * 4 + 3) * 64 + l) * 2));

    // ---- biases in D layout (tile1: j=4g+r; tile2: j=16+r on g==0) ----
    const float* bi = (wv == 0) ? b_ih0 : (wv == 1) ? b_ih1 : b_ih2;
    const float* bh = (wv == 0) ? b_hh0 : (wv == 1) ? b_hh1 : b_hh2;
    f32x4 bd1, bd2, w0lo, w0hi;
    #pragma unroll
    for (int r = 0; r < 4; ++r) {
        int j = 4 * g + r;
        bd1[r]  = bi[j] + bh[j];
        bd2[r]  = (g == 0) ? bi[16 + r] + bh[16 + r] : 0.f;
        w0lo[r] = w_ih0[j];
        w0hi[r] = (g == 0) ? w_ih0[16 + r] : 0.f;
    }

    // ---- recurrent state (own layer), in registers ----
    f16x4 Hlo = {}, Hhi = {};

    // ---- peeled diagonal pipeline ----
    __syncthreads();                       // staging visible
    if (wv == 0) W0SUP(0)
    __syncthreads();
    if (wv == 0) { W0SUP(1) } else if (wv == 1) { W1SUP(1) }
    for (int m = 2; m < NSUPER; ++m) {     // steady state: no range tests
        __syncthreads();
        if (wv == 0)      { W0SUP(m) }
        else if (wv == 1) { W1SUP(m) }
        else              { W2SUP(m) }
    }
    __syncthreads();
    if (wv == 1) { W1SUP(NSUPER) } else if (wv == 2) { W2SUP(NSUPER) }
    __syncthreads();
    if (wv == 2) { W2SUP(NSUPER + 1) }

    // ---- FC epilogue: wave2 holds h2(511) ----
    if (wv == 2) {
        float acc = 0.f;
        #pragma unroll
        for (int i = 0; i < 4; ++i)
            acc = fmaf((float)Hlo[i], fc_w[4 * g + i], acc);
        if (g == 0) {
            #pragma unroll
            for (int i = 0; i < 4; ++i)
                acc = fmaf((float)Hhi[i], fc_w[16 + i], acc);
        }
        acc += __shfl_xor(acc, 16);
        acc += __shfl_xor(acc, 32);
        if (l < 16) out[gb0 + l] = acc + fc_b[0];
    }
}

extern "C" void kernel_launch(void* const* d_in, const int* in_sizes, int n_in,
                              void* d_out, int out_size, void* d_ws, size_t ws_size,
                              hipStream_t stream) {
    const float* x     = (const float*)d_in[0];
    const float* w_ih0 = (const float*)d_in[1];
    const float* w_hh0 = (const float*)d_in[2];
    const float* b_ih0 = (const float*)d_in[3];
    const float* b_hh0 = (const float*)d_in[4];
    const float* w_ih1 = (const float*)d_in[5];
    const float* w_hh1 = (const float*)d_in[6];
    const float* b_ih1 = (const float*)d_in[7];
    const float* b_hh1 = (const float*)d_in[8];
    const float* w_ih2 = (const float*)d_in[9];
    const float* w_hh2 = (const float*)d_in[10];
    const float* b_ih2 = (const float*)d_in[11];
    const float* b_hh2 = (const float*)d_in[12];
    const float* fc_w  = (const float*)d_in[13];
    const float* fc_b  = (const float*)d_in[14];
    float* out = (float*)d_out;
    u32* wpk = (u32*)d_ws;   // 5 * 4 * 64 * 2 * 4 = 10240 B

    prep_w<<<1, 256, 0, stream>>>(w_hh0, w_ih1, w_hh1, w_ih2, w_hh2, wpk);

    rnn_mfma<<<B_TOTAL / 16, 192, 0, stream>>>(
        x, w_ih0, b_ih0, b_hh0, b_ih1, b_hh1, b_ih2, b_hh2,
        fc_w, fc_b, wpk, out);
}

// Round 23
// 161.716 us; speedup vs baseline: 1.6776x; 1.0318x over previous
//
#include <hip/hip_runtime.h>
#include <hip/hip_fp16.h>

// B=8192, T=512, IN=1, H=20, OUT=1
#define B_TOTAL 8192
#define T_LEN   512
#define H       20
#define KSTEP   4
#define NSUPER  (T_LEN / KSTEP)     // 128
#define CHUNK   128                 // x timesteps staged at once (32 super-ticks)
#define XSTRC   132                 // chunk row stride: 132%32=4 -> <=2-way (free)

typedef _Float16 f16x4 __attribute__((ext_vector_type(4)));
typedef float    f32x4 __attribute__((ext_vector_type(4)));
typedef unsigned int u32;

// 16x16x16 f16 MFMA (R18-validated): D lane(b,g) rows j=4g+r ; B lane(b,g)
// k=4g+i -> tanh(D)+pack IS next step's B-fragment, zero cross-lane ops.
#if defined(__HIP_DEVICE_COMPILE__)
  #if __has_builtin(__builtin_amdgcn_mfma_f32_16x16x16_f16)
    #define MFMA16(a, b, c) __builtin_amdgcn_mfma_f32_16x16x16_f16((a), (b), (c), 0, 0, 0)
  #elif __has_builtin(__builtin_amdgcn_mfma_f32_16x16x16f16)
    #define MFMA16(a, b, c) __builtin_amdgcn_mfma_f32_16x16x16f16((a), (b), (c), 0, 0, 0)
  #else
    #error "no 16x16x16 f16 MFMA builtin on device"
  #endif
#else
  #define MFMA16(a, b, c) (c)   // host parse stub
#endif

__device__ __forceinline__ float fast_tanh(float x) {
    float e = __builtin_amdgcn_exp2f(x * 2.885390081777927f);
    return fmaf(-2.0f, __builtin_amdgcn_rcpf(e + 1.0f), 1.0f);
}
__device__ __forceinline__ u32 pk2(float a, float b) {
    return __builtin_bit_cast(u32, __builtin_amdgcn_cvt_pkrtz(a, b));
}
__device__ __forceinline__ f16x4 u2f(uint2 v) { return __builtin_bit_cast(f16x4, v); }

// ---- prologue: pack 5 HxH matrices into 16x16x16 A-fragments (R18 verbatim) ----
__global__ void prep_w(const float* __restrict__ w_hh0, const float* __restrict__ w_ih1,
                       const float* __restrict__ w_hh1, const float* __restrict__ w_ih2,
                       const float* __restrict__ w_hh2, u32* __restrict__ ws)
{
    for (int e = threadIdx.x; e < 5 * 4 * 64; e += 256) {
        int l = e & 63, f = (e >> 6) & 3, m = e >> 8;
        const float* src = (m == 0) ? w_hh0 : (m == 1) ? w_ih1 :
                           (m == 2) ? w_hh1 : (m == 3) ? w_ih2 : w_hh2;
        int p = l & 15, g = l >> 4;
        int row = (f & 2) ? 16 + p : p;
        int kb  = ((f & 1) ? 16 : 0) + 4 * g;
        u32 d0 = 0, d1 = 0;
        if (row < H) {
            unsigned short h[4];
            #pragma unroll
            for (int i = 0; i < 4; ++i) {
                int k = kb + i;
                _Float16 v = (k < H) ? (_Float16)src[row * H + k] : (_Float16)0.f;
                h[i] = __builtin_bit_cast(unsigned short, v);
            }
            d0 = (u32)h[0] | ((u32)h[1] << 16);
            d1 = (u32)h[2] | ((u32)h[3] << 16);
        }
        ws[e * 2 + 0] = d0;
        ws[e * 2 + 1] = d1;
    }
}

// tanh(D1,D2) -> packed f16 state + uint4 for LDS handoff
#define TANHPK4(lo, hi, pkd, D1, D2) { \
    u32 a0 = pk2(fast_tanh((D1)[0]), fast_tanh((D1)[1])); \
    u32 a1 = pk2(fast_tanh((D1)[2]), fast_tanh((D1)[3])); \
    u32 a2 = pk2(fast_tanh((D2)[0]), fast_tanh((D2)[1])); \
    u32 a3 = pk2(fast_tanh((D2)[2]), fast_tanh((D2)[3])); \
    lo = u2f(make_uint2(a0, a1)); \
    hi = u2f(make_uint2(a2, a3)); \
    pkd = make_uint4(a0, a1, a2, a3); \
}

// wave-role superticks (KSTEP steps each). Numerics identical to R18.
#define W0SUP(m) { \
    f32x4 P1[KSTEP], P2[KSTEP]; \
    _Pragma("unroll") \
    for (int s = 0; s < KSTEP; ++s) { \
        float xv = xs[b][(KSTEP * (m) + s) & (CHUNK - 1)]; \
        _Pragma("unroll") \
        for (int r = 0; r < 4; ++r) { \
            P1[s][r] = fmaf(xv, w0lo[r], bd1[r]); \
            P2[s][r] = fmaf(xv, w0hi[r], bd2[r]); \
        } \
    } \
    _Pragma("unroll") \
    for (int s = 0; s < KSTEP; ++s) { \
        f32x4 D1 = MFMA16(RAlo1, Hlo, P1[s]); D1 = MFMA16(RAhi1, Hhi, D1); \
        f32x4 D2 = MFMA16(RAlo2, Hlo, P2[s]); D2 = MFMA16(RAhi2, Hhi, D2); \
        uint4 pk; \
        TANHPK4(Hlo, Hhi, pk, D1, D2) \
        h0b[(m) & 1][s][l] = pk; \
    } \
}

#define W1SUP(m) { \
    f32x4 P1[KSTEP], P2[KSTEP]; \
    _Pragma("unroll") \
    for (int s = 0; s < KSTEP; ++s) { \
        uint4 v = h0b[((m) - 1) & 1][s][l]; \
        f16x4 Blo = u2f(make_uint2(v.x, v.y)); \
        f16x4 Bhi = u2f(make_uint2(v.z, v.w)); \
        P1[s] = MFMA16(IAlo1, Blo, bd1); P1[s] = MFMA16(IAhi1, Bhi, P1[s]); \
        P2[s] = MFMA16(IAlo2, Blo, bd2); P2[s] = MFMA16(IAhi2, Bhi, P2[s]); \
    } \
    _Pragma("unroll") \
    for (int s = 0; s < KSTEP; ++s) { \
        f32x4 D1 = MFMA16(RAlo1, Hlo, P1[s]); D1 = MFMA16(RAhi1, Hhi, D1); \
        f32x4 D2 = MFMA16(RAlo2, Hlo, P2[s]); D2 = MFMA16(RAhi2, Hhi, D2); \
        uint4 pk; \
        TANHPK4(Hlo, Hhi, pk, D1, D2) \
        h1b[((m) - 1) & 1][s][l] = pk; \
    } \
}

#define W2SUP(m) { \
    f32x4 P1[KSTEP], P2[KSTEP]; \
    _Pragma("unroll") \
    for (int s = 0; s < KSTEP; ++s) { \
        uint4 v = h1b[(m) & 1][s][l]; \
        f16x4 Blo = u2f(make_uint2(v.x, v.y)); \
        f16x4 Bhi = u2f(make_uint2(v.z, v.w)); \
        P1[s] = MFMA16(IAlo1, Blo, bd1); P1[s] = MFMA16(IAhi1, Bhi, P1[s]); \
        P2[s] = MFMA16(IAlo2, Blo, bd2); P2[s] = MFMA16(IAhi2, Bhi, P2[s]); \
    } \
    _Pragma("unroll") \
    for (int s = 0; s < KSTEP; ++s) { \
        f32x4 D1 = MFMA16(RAlo1, Hlo, P1[s]); D1 = MFMA16(RAhi1, Hhi, D1); \
        f32x4 D2 = MFMA16(RAlo2, Hlo, P2[s]); D2 = MFMA16(RAhi2, Hhi, D2); \
        uint4 pk; \
        TANHPK4(Hlo, Hhi, pk, D1, D2) \
    } \
}

// 3 waves/block (one layer each), 16 batches/block, KSTEP=4, peeled pipeline.
// LDS ~25 KB (x staged in 128-step chunks, wave0 restages) -> up to 6
// blocks/CU = 18 waves/CU: co-resident blocks fill each other's barrier gaps.
__global__ __launch_bounds__(192, 4) void rnn_mfma(
    const float* __restrict__ x,
    const float* __restrict__ w_ih0,
    const float* __restrict__ b_ih0, const float* __restrict__ b_hh0,
    const float* __restrict__ b_ih1, const float* __restrict__ b_hh1,
    const float* __restrict__ b_ih2, const float* __restrict__ b_hh2,
    const float* __restrict__ fc_w,  const float* __restrict__ fc_b,
    const u32* __restrict__ wpk,
    float* __restrict__ out)
{
    __shared__ __align__(16) float xs[16][XSTRC];        // 128-step chunk (8.4 KB)
    __shared__ __align__(16) uint4 h0b[2][KSTEP][64];    // 8 KB, wv0 -> wv1
    __shared__ __align__(16) uint4 h1b[2][KSTEP][64];    // 8 KB, wv1 -> wv2

    const int tid = threadIdx.x;
    const int wv  = tid >> 6;
    const int l   = tid & 63;
    const int b   = l & 15;
    const int g   = l >> 4;
    const int gb0 = blockIdx.x * 16;

    // ---- stage x chunk 0 (cooperative, all 192 threads) ----
    for (int i = tid; i < 16 * (CHUNK / 4); i += 192) {
        int row = i >> 5, col4 = i & 31;
        *(float4*)&xs[row][col4 * 4] =
            *(const float4*)(x + (size_t)(gb0 + row) * T_LEN + col4 * 4);
    }

    // ---- per-wave weight A-fragments ----
    const int mA = (wv == 1) ? 1 : 3;
    const int mB = (wv == 0) ? 0 : (wv == 1) ? 2 : 4;
    f16x4 IAlo1 = {}, IAhi1 = {}, IAlo2 = {}, IAhi2 = {};
    if (wv != 0) {
        IAlo1 = u2f(*(const uint2*)(wpk + ((mA * 4 + 0) * 64 + l) * 2));
        IAhi1 = u2f(*(const uint2*)(wpk + ((mA * 4 + 1) * 64 + l) * 2));
        IAlo2 = u2f(*(const uint2*)(wpk + ((mA * 4 + 2) * 64 + l) * 2));
        IAhi2 = u2f(*(const uint2*)(wpk + ((mA * 4 + 3) * 64 + l) * 2));
    }
    const f16x4 RAlo1 = u2f(*(const uint2*)(wpk + ((mB * 4 + 0) * 64 + l) * 2));
    const f16x4 RAhi1 = u2f(*(const uint2*)(wpk + ((mB * 4 + 1) * 64 + l) * 2));
    const f16x4 RAlo2 = u2f(*(const uint2*)(wpk + ((mB * 4 + 2) * 64 + l) * 2));
    const f16x4 RAhi2 = u2f(*(const uint2*)(wpk + ((mB * 4 + 3) * 64 + l) * 2));

    // ---- biases in D layout (tile1: j=4g+r; tile2: j=16+r on g==0) ----
    const float* bi = (wv == 0) ? b_ih0 : (wv == 1) ? b_ih1 : b_ih2;
    const float* bh = (wv == 0) ? b_hh0 : (wv == 1) ? b_hh1 : b_hh2;
    f32x4 bd1, bd2, w0lo, w0hi;
    #pragma unroll
    for (int r = 0; r < 4; ++r) {
        int j = 4 * g + r;
        bd1[r]  = bi[j] + bh[j];
        bd2[r]  = (g == 0) ? bi[16 + r] + bh[16 + r] : 0.f;
        w0lo[r] = w_ih0[j];
        w0hi[r] = (g == 0) ? w_ih0[16 + r] : 0.f;
    }

    // ---- recurrent state (own layer), in registers ----
    f16x4 Hlo = {}, Hhi = {};

    // ---- peeled diagonal pipeline ----
    __syncthreads();                       // staging visible
    if (wv == 0) W0SUP(0)
    __syncthreads();
    if (wv == 0) { W0SUP(1) } else if (wv == 1) { W1SUP(1) }
    for (int m = 2; m < NSUPER; ++m) {     // steady state
        __syncthreads();
        if (wv == 0) {
            // restage next x chunk at 128-step boundaries (wave0-private data,
            // same-wave in-order DS -> no extra barrier needed)
            if ((m & 31) == 0) {
                const int tc = (m >> 5) * CHUNK;
                for (int i = l; i < 16 * (CHUNK / 4); i += 64) {
                    int row = i >> 5, col4 = i & 31;
                    *(float4*)&xs[row][col4 * 4] =
                        *(const float4*)(x + (size_t)(gb0 + row) * T_LEN + tc + col4 * 4);
                }
            }
            W0SUP(m)
        }
        else if (wv == 1) { W1SUP(m) }
        else              { W2SUP(m) }
    }
    __syncthreads();
    if (wv == 1) { W1SUP(NSUPER) } else if (wv == 2) { W2SUP(NSUPER) }
    __syncthreads();
    if (wv == 2) { W2SUP(NSUPER + 1) }

    // ---- FC epilogue: wave2 holds h2(511) ----
    if (wv == 2) {
        float acc = 0.f;
        #pragma unroll
        for (int i = 0; i < 4; ++i)
            acc = fmaf((float)Hlo[i], fc_w[4 * g + i], acc);
        if (g == 0) {
            #pragma unroll
            for (int i = 0; i < 4; ++i)
                acc = fmaf((float)Hhi[i], fc_w[16 + i], acc);
        }
        acc += __shfl_xor(acc, 16);
        acc += __shfl_xor(acc, 32);
        if (l < 16) out[gb0 + l] = acc + fc_b[0];
    }
}

extern "C" void kernel_launch(void* const* d_in, const int* in_sizes, int n_in,
                              void* d_out, int out_size, void* d_ws, size_t ws_size,
                              hipStream_t stream) {
    const float* x     = (const float*)d_in[0];
    const float* w_ih0 = (const float*)d_in[1];
    const float* w_hh0 = (const float*)d_in[2];
    const float* b_ih0 = (const float*)d_in[3];
    const float* b_hh0 = (const float*)d_in[4];
    const float* w_ih1 = (const float*)d_in[5];
    const float* w_hh1 = (const float*)d_in[6];
    const float* b_ih1 = (const float*)d_in[7];
    const float* b_hh1 = (const float*)d_in[8];
    const float* w_ih2 = (const float*)d_in[9];
    const float* w_hh2 = (const float*)d_in[10];
    const float* b_ih2 = (const float*)d_in[11];
    const float* b_hh2 = (const float*)d_in[12];
    const float* fc_w  = (const float*)d_in[13];
    const float* fc_b  = (const float*)d_in[14];
    float* out = (float*)d_out;
    u32* wpk = (u32*)d_ws;   // 5 * 4 * 64 * 2 * 4 = 10240 B

    prep_w<<<1, 256, 0, stream>>>(w_hh0, w_ih1, w_hh1, w_ih2, w_hh2, wpk);

    rnn_mfma<<<B_TOTAL / 16, 192, 0, stream>>>(
        x, w_ih0, b_ih0, b_hh0, b_ih1, b_hh1, b_ih2, b_hh2,
        fc_w, fc_b, wpk, out);
}